// Round 3
// baseline (2784.061 us; speedup 1.0000x reference)
//
#include <hip/hip_runtime.h>
#include <math.h>
#include <stdint.h>

#define B_ 32
#define C_ 32
#define H_ 16
#define V_ 8192
#define HW_ 256
#define NELEM (B_*C_*H_*H_)   // 262144
#define ESTRIDE 36            // padded emb row: 32 floats + e2 + 3 pad (144 B)

__device__ __forceinline__ unsigned int fkey(float f) {
    unsigned int u = __float_as_uint(f);
    return (u & 0x80000000u) ? ~u : (u | 0x80000000u);
}

__global__ void __launch_bounds__(256) k_init(
    const float* __restrict__ f, const float* __restrict__ emb,
    float* __restrict__ f_rest, float* __restrict__ f_hat,
    float* __restrict__ embp, float* __restrict__ lossAcc)
{
    int i = blockIdx.x*256 + threadIdx.x;
    if (i < NELEM) { float v = f[i]; f_rest[i] = v; f_hat[i] = 0.f; }
    if (i < V_) {
        const float4* e4 = (const float4*)(emb + (size_t)i*C_);
        float4* op = (float4*)(embp + (size_t)i*ESTRIDE);
        float s = 0.f;
        #pragma unroll
        for (int cc = 0; cc < 8; ++cc) {
            float4 ev = e4[cc];
            op[cc] = ev;
            s += ev.x*ev.x + ev.y*ev.y + ev.z*ev.z + ev.w*ev.w;
        }
        embp[(size_t)i*ESTRIDE + 32] = s;
    }
    if (i == 0) lossAcc[0] = 0.f;
}

// area pool f_rest -> z[n][c]; also init best slots
__global__ void __launch_bounds__(256) k_pool(
    const float* __restrict__ f_rest, float* __restrict__ z,
    unsigned long long* __restrict__ best, int pn, int N)
{
    int gid = blockIdx.x*256 + threadIdx.x;
    if (gid >= N*C_) return;
    int c = gid & 31;
    int n = gid >> 5;
    if (c == 0) best[n] = ~0ull;
    int pp = pn*pn;
    int b = n / pp;
    int rem = n - b*pp;
    int p = rem / pn;
    int q = rem - p*pn;
    int hs = (p*H_)/pn,  he = ((p+1)*H_ + pn-1)/pn;
    int ws = (q*H_)/pn,  we = ((q+1)*H_ + pn-1)/pn;
    const float* base = f_rest + ((size_t)(b*C_ + c))*HW_;
    float s = 0.f;
    for (int hh = hs; hh < he; ++hh) {
        #pragma unroll 4
        for (int ww = ws; ww < we; ++ww)
            s += base[hh*H_ + ww];
    }
    float inv = (1.f/(float)(he-hs)) * (1.f/(float)(we-ws));
    z[(size_t)n*C_ + c] = s * inv;
}

// VQ: lane = query; emb rows stream through VMEM with depth-4 rotating
// VGPR buffers (counted vmcnt waits by compiler); accumulate d = e2 - 2*z.e
__global__ void __launch_bounds__(256, 2) k_vq(
    const float* __restrict__ z, const float* __restrict__ embp,
    unsigned long long* __restrict__ best, int N, int lvs)
{
    __shared__ unsigned long long lb[64];
    int tid  = threadIdx.x;
    int lane = tid & 63;
    int wave = blockIdx.x*4 + (tid >> 6);
    int vs   = 1 << lvs;
    int qt   = wave >> lvs;
    int vc   = wave & (vs-1);
    int vlen = V_ >> lvs;          // 64..256, multiple of 4
    int v0   = vc * vlen;
    int n    = qt*64 + lane;
    bool act = (n < N);
    if (tid < 64) lb[tid] = ~0ull;
    __syncthreads();

    const float4* zp = (const float4*)(z + (size_t)(act ? n : 0)*C_);
    float zm[32];
    #pragma unroll
    for (int cc = 0; cc < 8; ++cc) {
        float4 t = zp[cc];
        zm[cc*4+0] = -2.f*t.x; zm[cc*4+1] = -2.f*t.y;
        zm[cc*4+2] = -2.f*t.z; zm[cc*4+3] = -2.f*t.w;
    }

    const float4* rp = (const float4*)(embp + (size_t)v0*ESTRIDE);
    float4 buf[4][9];
    #pragma unroll
    for (int j = 0; j < 4; ++j) {
        #pragma unroll
        for (int k = 0; k < 9; ++k) buf[j][k] = rp[j*9 + k];
    }

    float dmin = __builtin_inff();
    int imin = 0;
    for (int v2 = 0; v2 < vlen; v2 += 4) {
        #pragma unroll
        for (int j = 0; j < 4; ++j) {
            float a0 = buf[j][8].x;   // e2
            float a1 = 0.f, a2 = 0.f, a3 = 0.f;
            #pragma unroll
            for (int cc = 0; cc < 8; ++cc) {
                float4 ev = buf[j][cc];
                a0 = fmaf(zm[4*cc+0], ev.x, a0);
                a1 = fmaf(zm[4*cc+1], ev.y, a1);
                a2 = fmaf(zm[4*cc+2], ev.z, a2);
                a3 = fmaf(zm[4*cc+3], ev.w, a3);
            }
            float d = (a0+a1)+(a2+a3);
            if (d < dmin) { dmin = d; imin = v2 + j; }
            // prefetch row v2+j+4 (clamped inside chunk; tail loads unused)
            int vn = v2 + j + 4;
            int voff = (vn < vlen) ? vn : 0;
            const float4* pf = rp + (size_t)voff*9;
            #pragma unroll
            for (int k = 0; k < 9; ++k) buf[j][k] = pf[k];
        }
    }

    unsigned long long key =
        ((unsigned long long)fkey(dmin) << 32) | (unsigned int)(imin + v0);
    atomicMin(&lb[lane], key);
    __syncthreads();
    if (tid < 64) {
        int n0 = ((blockIdx.x*4) >> lvs)*64 + tid;
        if (n0 < N) atomicMin(best + n0, lb[tid]);
    }
}

__device__ __forceinline__ void cubic_taps(int i, int pn, float* wt, int* col) {
    double src = ((double)i + 0.5) * ((double)pn / 16.0) - 0.5;
    double fl = floor(src);
    const double A = -0.75;
    #pragma unroll
    for (int k = 0; k < 4; ++k) {
        double j = fl - 1.0 + (double)k;
        double d = fabs(src - j);
        double w;
        if (d <= 1.0)      w = ((A+2.0)*d - (A+3.0))*d*d + 1.0;
        else if (d < 2.0)  w = ((A*d - 5.0*A)*d + 8.0*A)*d - 4.0*A;
        else               w = 0.0;
        wt[k] = (float)w;
        int jj = (int)j;
        col[k] = jj < 0 ? 0 : (jj > pn-1 ? pn-1 : jj);
    }
}

// bicubic upsample (emb gather) -> LDS, 3x3 conv + Phi blend,
// f_hat += , f_rest -= , loss partial
__global__ void __launch_bounds__(256) k_upphi(
    const unsigned long long* __restrict__ best,
    const float* __restrict__ emb,
    const float* __restrict__ cw, const float* __restrict__ cb,
    const float* __restrict__ forig,
    float* __restrict__ f_hat, float* __restrict__ f_rest,
    float* __restrict__ lossAcc, int pn)
{
    __shared__ float hup[16][16][33];
    __shared__ float red[4];
    int bi = blockIdx.x >> 3;
    int g  = blockIdx.x & 7;
    int tid = threadIdx.x;
    int h = tid >> 4, w = tid & 15;

    float wh[4]; int th[4];
    float wwt[4]; int tw[4];
    cubic_taps(h, pn, wh, th);
    cubic_taps(w, pn, wwt, tw);

    float acc[32];
    #pragma unroll
    for (int c = 0; c < 32; ++c) acc[c] = 0.f;
    const unsigned long long* bptr = best + bi*pn*pn;
    for (int i = 0; i < 4; ++i) {
        if (wh[i] == 0.f) continue;
        for (int j = 0; j < 4; ++j) {
            float wt = wh[i]*wwt[j];
            if (wt == 0.f) continue;
            unsigned int idx = (unsigned int)(bptr[th[i]*pn + tw[j]] & 0xffffffffull);
            const float4* e4 = (const float4*)(emb + (size_t)idx*C_);
            #pragma unroll
            for (int cc = 0; cc < 8; ++cc) {
                float4 ev = e4[cc];
                acc[cc*4+0] = fmaf(wt, ev.x, acc[cc*4+0]);
                acc[cc*4+1] = fmaf(wt, ev.y, acc[cc*4+1]);
                acc[cc*4+2] = fmaf(wt, ev.z, acc[cc*4+2]);
                acc[cc*4+3] = fmaf(wt, ev.w, acc[cc*4+3]);
            }
        }
    }
    #pragma unroll
    for (int c = 0; c < 32; ++c) hup[h][w][c] = acc[c];
    __syncthreads();

    int co0 = g*4;
    float o4[4];
    #pragma unroll
    for (int k = 0; k < 4; ++k) o4[k] = cb[co0+k];
    for (int ci = 0; ci < 32; ++ci) {
        float hv[9];
        #pragma unroll
        for (int dh = 0; dh < 3; ++dh) {
            int hh = h + dh - 1;
            #pragma unroll
            for (int dw = 0; dw < 3; ++dw) {
                int ww2 = w + dw - 1;
                bool ok = (hh >= 0) & (hh < 16) & (ww2 >= 0) & (ww2 < 16);
                hv[dh*3+dw] = ok ? hup[hh & 15][ww2 & 15][ci] : 0.f;
            }
        }
        #pragma unroll
        for (int k = 0; k < 4; ++k) {
            const float* wr = cw + ((size_t)(co0+k)*C_ + ci)*9;
            float s = 0.f;
            #pragma unroll
            for (int p2 = 0; p2 < 9; ++p2) s = fmaf(hv[p2], wr[p2], s);
            o4[k] += s;
        }
    }

    float sq = 0.f;
    #pragma unroll
    for (int k = 0; k < 4; ++k) {
        float hv0 = hup[h][w][co0+k];
        float outv = 0.5f*hv0 + 0.5f*o4[k];
        size_t off = ((size_t)(bi*C_ + co0 + k))*HW_ + h*16 + w;
        float fh = f_hat[off] + outv;
        f_hat[off] = fh;
        f_rest[off] = f_rest[off] - outv;
        float df = fh - forig[off];
        sq = fmaf(df, df, sq);
    }
    #pragma unroll
    for (int o2 = 32; o2 > 0; o2 >>= 1) sq += __shfl_down(sq, o2, 64);
    if ((tid & 63) == 0) red[tid >> 6] = sq;
    __syncthreads();
    if (tid == 0) atomicAdd(lossAcc, (red[0]+red[1])+(red[2]+red[3]));
}

__global__ void __launch_bounds__(256) k_final(
    const float* __restrict__ f_hat, const float* __restrict__ lossAcc,
    float* __restrict__ out)
{
    int i = blockIdx.x*256 + threadIdx.x;
    if (i < NELEM) out[i] = f_hat[i];
    if (i == 0) out[NELEM] = lossAcc[0] * 1.25f / ((float)NELEM * 10.f);
}

extern "C" void kernel_launch(void* const* d_in, const int* in_sizes, int n_in,
                              void* d_out, int out_size, void* d_ws, size_t ws_size,
                              hipStream_t stream)
{
    const float* f   = (const float*)d_in[0];
    const float* emb = (const float*)d_in[1];
    const float* cw  = (const float*)d_in[2];
    const float* cb  = (const float*)d_in[3];
    float* out = (float*)d_out;
    char* ws = (char*)d_ws;
    unsigned long long* best = (unsigned long long*)ws;       // 8192 * 8 B
    float* f_rest = (float*)(ws + 65536);
    float* f_hat  = f_rest + NELEM;
    float* z      = f_hat + NELEM;
    float* embp   = z + NELEM;                    // (V_+2)*ESTRIDE floats
    float* lossAcc = embp + (size_t)(V_+2)*ESTRIDE;

    // Replicate PHI_IDX with numpy-linspace double semantics (no FP contraction)
    volatile double a   = 1.0/3.0/4.0;
    volatile double bb  = 1.0 - a;
    volatile double stp = (bb - a) / 3.0;
    double ticks[4];
    for (int i = 0; i < 4; ++i) { volatile double m = (double)i * stp; ticks[i] = m + a; }
    ticks[3] = bb;
    static const int pns[10] = {1,2,3,4,5,6,8,10,13,16};
    int phi_idx[10];
    for (int si = 0; si < 10; ++si) {
        volatile double x = (double)si / 9.0;
        int bi = 0; double bd = fabs(ticks[0] - x);
        for (int k = 1; k < 4; ++k) {
            double d = fabs(ticks[k] - x);
            if (d < bd) { bd = d; bi = k; }
        }
        phi_idx[si] = bi;
    }

    k_init<<<1024, 256, 0, stream>>>(f, emb, f_rest, f_hat, embp, lossAcc);

    // V-split log2 per scale: vlen stays a multiple of 4, >=64
    static const int lvss[10] = {7,7,7,7,7,7,7,7,6,6};
    for (int si = 0; si < 10; ++si) {
        int pn = pns[si];
        int N = B_*pn*pn;
        int pthr = N*C_;
        k_pool<<<(pthr+255)/256, 256, 0, stream>>>(f_rest, z, best, pn, N);
        int qtiles = (N+63)/64;
        int lvs = lvss[si];
        int waves = qtiles << lvs;
        k_vq<<<waves/4, 256, 0, stream>>>(z, embp, best, N, lvs);
        const float* cwp = cw + (size_t)phi_idx[si]*C_*C_*9;
        const float* cbp = cb + (size_t)phi_idx[si]*C_;
        k_upphi<<<B_*8, 256, 0, stream>>>(best, emb, cwp, cbp, f, f_hat, f_rest,
                                          lossAcc, pn);
    }
    k_final<<<1024, 256, 0, stream>>>(f_hat, lossAcc, out);
}

// Round 4
// 550.757 us; speedup vs baseline: 5.0550x; 5.0550x over previous
//
#include <hip/hip_runtime.h>
#include <math.h>
#include <stdint.h>

#define B_ 32
#define C_ 32
#define H_ 16
#define V_ 8192
#define HW_ 256
#define NELEM (B_*C_*H_*H_)   // 262144
#define ESTRIDE 36            // padded emb row: 32 floats + e2 + 3 pad (144 B)

__device__ __forceinline__ unsigned int fkey(float f) {
    unsigned int u = __float_as_uint(f);
    return (u & 0x80000000u) ? ~u : (u | 0x80000000u);
}

__global__ void __launch_bounds__(256) k_init(
    const float* __restrict__ f, const float* __restrict__ emb,
    float* __restrict__ f_rest, float* __restrict__ f_hat,
    float* __restrict__ embp, float* __restrict__ lossAcc)
{
    int i = blockIdx.x*256 + threadIdx.x;
    if (i < NELEM) { float v = f[i]; f_rest[i] = v; f_hat[i] = 0.f; }
    if (i < V_) {
        const float4* e4 = (const float4*)(emb + (size_t)i*C_);
        float4* op = (float4*)(embp + (size_t)i*ESTRIDE);
        float s = 0.f;
        #pragma unroll
        for (int cc = 0; cc < 8; ++cc) {
            float4 ev = e4[cc];
            op[cc] = ev;
            s += ev.x*ev.x + ev.y*ev.y + ev.z*ev.z + ev.w*ev.w;
        }
        embp[(size_t)i*ESTRIDE + 32] = s;
    }
    if (i == 0) lossAcc[0] = 0.f;
}

// area pool f_rest -> z[n][c]; also init best slots
__global__ void __launch_bounds__(256) k_pool(
    const float* __restrict__ f_rest, float* __restrict__ z,
    unsigned long long* __restrict__ best, int pn, int N)
{
    int gid = blockIdx.x*256 + threadIdx.x;
    if (gid >= N*C_) return;
    int c = gid & 31;
    int n = gid >> 5;
    if (c == 0) best[n] = ~0ull;
    int pp = pn*pn;
    int b = n / pp;
    int rem = n - b*pp;
    int p = rem / pn;
    int q = rem - p*pn;
    int hs = (p*H_)/pn,  he = ((p+1)*H_ + pn-1)/pn;
    int ws = (q*H_)/pn,  we = ((q+1)*H_ + pn-1)/pn;
    const float* base = f_rest + ((size_t)(b*C_ + c))*HW_;
    float s = 0.f;
    for (int hh = hs; hh < he; ++hh) {
        #pragma unroll 4
        for (int ww = ws; ww < we; ++ww)
            s += base[hh*H_ + ww];
    }
    float inv = (1.f/(float)(he-hs)) * (1.f/(float)(we-ws));
    z[(size_t)n*C_ + c] = s * inv;
}

// VQ: block = one 128-query tile (2 queries/lane) x one V-chunk staged in LDS.
// Waves sweep disjoint row-quarters with wave-uniform ds_read_b128 (broadcast).
__global__ void __launch_bounds__(256) k_vq(
    const float* __restrict__ z, const float* __restrict__ embp,
    unsigned long long* __restrict__ best, int N, int lvc)
{
    __shared__ float4 se[2304];                 // up to 256 rows * 9 float4
    __shared__ unsigned long long lb[128];
    int tid  = threadIdx.x;
    int lane = tid & 63;
    int wid  = tid >> 6;
    int vchunk = V_ >> lvc;                     // rows per block (64..256)
    int vc = blockIdx.x & ((1 << lvc) - 1);
    int qt = blockIdx.x >> lvc;
    int v0b = vc * vchunk;
    int rw  = vchunk >> 2;                      // rows per wave
    int v0w = v0b + wid*rw;

    if (tid < 128) lb[tid] = ~0ull;
    const float4* gsrc = (const float4*)(embp + (size_t)v0b*ESTRIDE);
    int cnt = vchunk*9;
    for (int i = tid; i < cnt; i += 256) se[i] = gsrc[i];
    __syncthreads();

    int n0 = qt*128 + lane;
    int n1 = n0 + 64;
    bool a0v = (n0 < N), a1v = (n1 < N);
    const float4* zp0 = (const float4*)(z + (size_t)(a0v ? n0 : 0)*C_);
    const float4* zp1 = (const float4*)(z + (size_t)(a1v ? n1 : 0)*C_);
    float zm0[32], zm1[32];
    #pragma unroll
    for (int cc = 0; cc < 8; ++cc) {
        float4 t0 = zp0[cc];
        float4 t1 = zp1[cc];
        zm0[4*cc+0] = -2.f*t0.x; zm0[4*cc+1] = -2.f*t0.y;
        zm0[4*cc+2] = -2.f*t0.z; zm0[4*cc+3] = -2.f*t0.w;
        zm1[4*cc+0] = -2.f*t1.x; zm1[4*cc+1] = -2.f*t1.y;
        zm1[4*cc+2] = -2.f*t1.z; zm1[4*cc+3] = -2.f*t1.w;
    }

    float dmin0 = __builtin_inff(), dmin1 = __builtin_inff();
    int imin0 = v0w, imin1 = v0w;
    const float4* sp = se + (size_t)(wid*rw)*9;
    for (int r = 0; r < rw; ++r) {
        float4 b0 = sp[0], b1 = sp[1], b2 = sp[2], b3 = sp[3];
        float4 b4 = sp[4], b5 = sp[5], b6 = sp[6], b7 = sp[7];
        float  e2 = sp[8].x;
        sp += 9;
        float p00 = e2, p01 = 0.f, p02 = 0.f, p03 = 0.f;
        float p10 = e2, p11 = 0.f, p12 = 0.f, p13 = 0.f;
        #define ROWQ(BB, CC)                                        \
            p00 = fmaf(zm0[4*CC+0], BB.x, p00);                     \
            p01 = fmaf(zm0[4*CC+1], BB.y, p01);                     \
            p02 = fmaf(zm0[4*CC+2], BB.z, p02);                     \
            p03 = fmaf(zm0[4*CC+3], BB.w, p03);                     \
            p10 = fmaf(zm1[4*CC+0], BB.x, p10);                     \
            p11 = fmaf(zm1[4*CC+1], BB.y, p11);                     \
            p12 = fmaf(zm1[4*CC+2], BB.z, p12);                     \
            p13 = fmaf(zm1[4*CC+3], BB.w, p13);
        ROWQ(b0, 0) ROWQ(b1, 1) ROWQ(b2, 2) ROWQ(b3, 3)
        ROWQ(b4, 4) ROWQ(b5, 5) ROWQ(b6, 6) ROWQ(b7, 7)
        #undef ROWQ
        float d0 = (p00+p01)+(p02+p03);
        float d1 = (p10+p11)+(p12+p13);
        if (d0 < dmin0) { dmin0 = d0; imin0 = v0w + r; }
        if (d1 < dmin1) { dmin1 = d1; imin1 = v0w + r; }
    }

    if (a0v) {
        unsigned long long k0 =
            ((unsigned long long)fkey(dmin0) << 32) | (unsigned int)imin0;
        atomicMin(&lb[lane], k0);
    }
    if (a1v) {
        unsigned long long k1 =
            ((unsigned long long)fkey(dmin1) << 32) | (unsigned int)imin1;
        atomicMin(&lb[lane + 64], k1);
    }
    __syncthreads();
    if (tid < 128) {
        int n = qt*128 + tid;
        if (n < N) atomicMin(best + n, lb[tid]);
    }
}

__device__ __forceinline__ void cubic_taps(int i, int pn, float* wt, int* col) {
    double src = ((double)i + 0.5) * ((double)pn / 16.0) - 0.5;
    double fl = floor(src);
    const double A = -0.75;
    #pragma unroll
    for (int k = 0; k < 4; ++k) {
        double j = fl - 1.0 + (double)k;
        double d = fabs(src - j);
        double w;
        if (d <= 1.0)      w = ((A+2.0)*d - (A+3.0))*d*d + 1.0;
        else if (d < 2.0)  w = ((A*d - 5.0*A)*d + 8.0*A)*d - 4.0*A;
        else               w = 0.0;
        wt[k] = (float)w;
        int jj = (int)j;
        col[k] = jj < 0 ? 0 : (jj > pn-1 ? pn-1 : jj);
    }
}

// bicubic upsample (emb gather) -> LDS, 3x3 conv + Phi blend,
// f_hat += , f_rest -= , loss partial
__global__ void __launch_bounds__(256) k_upphi(
    const unsigned long long* __restrict__ best,
    const float* __restrict__ emb,
    const float* __restrict__ cw, const float* __restrict__ cb,
    const float* __restrict__ forig,
    float* __restrict__ f_hat, float* __restrict__ f_rest,
    float* __restrict__ lossAcc, int pn)
{
    __shared__ float hup[16][16][33];
    __shared__ float red[4];
    int bi = blockIdx.x >> 3;
    int g  = blockIdx.x & 7;
    int tid = threadIdx.x;
    int h = tid >> 4, w = tid & 15;

    float wh[4]; int th[4];
    float wwt[4]; int tw[4];
    cubic_taps(h, pn, wh, th);
    cubic_taps(w, pn, wwt, tw);

    float acc[32];
    #pragma unroll
    for (int c = 0; c < 32; ++c) acc[c] = 0.f;
    const unsigned long long* bptr = best + bi*pn*pn;
    for (int i = 0; i < 4; ++i) {
        if (wh[i] == 0.f) continue;
        for (int j = 0; j < 4; ++j) {
            float wt = wh[i]*wwt[j];
            if (wt == 0.f) continue;
            unsigned int idx = (unsigned int)(bptr[th[i]*pn + tw[j]] & 0xffffffffull);
            const float4* e4 = (const float4*)(emb + (size_t)idx*C_);
            #pragma unroll
            for (int cc = 0; cc < 8; ++cc) {
                float4 ev = e4[cc];
                acc[cc*4+0] = fmaf(wt, ev.x, acc[cc*4+0]);
                acc[cc*4+1] = fmaf(wt, ev.y, acc[cc*4+1]);
                acc[cc*4+2] = fmaf(wt, ev.z, acc[cc*4+2]);
                acc[cc*4+3] = fmaf(wt, ev.w, acc[cc*4+3]);
            }
        }
    }
    #pragma unroll
    for (int c = 0; c < 32; ++c) hup[h][w][c] = acc[c];
    __syncthreads();

    int co0 = g*4;
    float o4[4];
    #pragma unroll
    for (int k = 0; k < 4; ++k) o4[k] = cb[co0+k];
    for (int ci = 0; ci < 32; ++ci) {
        float hv[9];
        #pragma unroll
        for (int dh = 0; dh < 3; ++dh) {
            int hh = h + dh - 1;
            #pragma unroll
            for (int dw = 0; dw < 3; ++dw) {
                int ww2 = w + dw - 1;
                bool ok = (hh >= 0) & (hh < 16) & (ww2 >= 0) & (ww2 < 16);
                hv[dh*3+dw] = ok ? hup[hh & 15][ww2 & 15][ci] : 0.f;
            }
        }
        #pragma unroll
        for (int k = 0; k < 4; ++k) {
            const float* wr = cw + ((size_t)(co0+k)*C_ + ci)*9;
            float s = 0.f;
            #pragma unroll
            for (int p2 = 0; p2 < 9; ++p2) s = fmaf(hv[p2], wr[p2], s);
            o4[k] += s;
        }
    }

    float sq = 0.f;
    #pragma unroll
    for (int k = 0; k < 4; ++k) {
        float hv0 = hup[h][w][co0+k];
        float outv = 0.5f*hv0 + 0.5f*o4[k];
        size_t off = ((size_t)(bi*C_ + co0 + k))*HW_ + h*16 + w;
        float fh = f_hat[off] + outv;
        f_hat[off] = fh;
        f_rest[off] = f_rest[off] - outv;
        float df = fh - forig[off];
        sq = fmaf(df, df, sq);
    }
    #pragma unroll
    for (int o2 = 32; o2 > 0; o2 >>= 1) sq += __shfl_down(sq, o2, 64);
    if ((tid & 63) == 0) red[tid >> 6] = sq;
    __syncthreads();
    if (tid == 0) atomicAdd(lossAcc, (red[0]+red[1])+(red[2]+red[3]));
}

__global__ void __launch_bounds__(256) k_final(
    const float* __restrict__ f_hat, const float* __restrict__ lossAcc,
    float* __restrict__ out)
{
    int i = blockIdx.x*256 + threadIdx.x;
    if (i < NELEM) out[i] = f_hat[i];
    if (i == 0) out[NELEM] = lossAcc[0] * 1.25f / ((float)NELEM * 10.f);
}

extern "C" void kernel_launch(void* const* d_in, const int* in_sizes, int n_in,
                              void* d_out, int out_size, void* d_ws, size_t ws_size,
                              hipStream_t stream)
{
    const float* f   = (const float*)d_in[0];
    const float* emb = (const float*)d_in[1];
    const float* cw  = (const float*)d_in[2];
    const float* cb  = (const float*)d_in[3];
    float* out = (float*)d_out;
    char* ws = (char*)d_ws;
    unsigned long long* best = (unsigned long long*)ws;       // 8192 * 8 B
    float* f_rest = (float*)(ws + 65536);
    float* f_hat  = f_rest + NELEM;
    float* z      = f_hat + NELEM;
    float* embp   = z + NELEM;                    // (V_+2)*ESTRIDE floats
    float* lossAcc = embp + (size_t)(V_+2)*ESTRIDE;

    // Replicate PHI_IDX with numpy-linspace double semantics (no FP contraction)
    volatile double a   = 1.0/3.0/4.0;
    volatile double bb  = 1.0 - a;
    volatile double stp = (bb - a) / 3.0;
    double ticks[4];
    for (int i = 0; i < 4; ++i) { volatile double m = (double)i * stp; ticks[i] = m + a; }
    ticks[3] = bb;
    static const int pns[10] = {1,2,3,4,5,6,8,10,13,16};
    int phi_idx[10];
    for (int si = 0; si < 10; ++si) {
        volatile double x = (double)si / 9.0;
        int bi = 0; double bd = fabs(ticks[0] - x);
        for (int k = 1; k < 4; ++k) {
            double d = fabs(ticks[k] - x);
            if (d < bd) { bd = d; bi = k; }
        }
        phi_idx[si] = bi;
    }

    k_init<<<1024, 256, 0, stream>>>(f, emb, f_rest, f_hat, embp, lossAcc);

    // log2(V-chunks) per scale: small scales split V finer for parallelism
    static const int lvcs[10] = {7,7,7,7,6,6,5,5,5,5};
    for (int si = 0; si < 10; ++si) {
        int pn = pns[si];
        int N = B_*pn*pn;
        int pthr = N*C_;
        k_pool<<<(pthr+255)/256, 256, 0, stream>>>(f_rest, z, best, pn, N);
        int qtiles = (N+127)/128;
        int lvc = lvcs[si];
        k_vq<<<qtiles << lvc, 256, 0, stream>>>(z, embp, best, N, lvc);
        const float* cwp = cw + (size_t)phi_idx[si]*C_*C_*9;
        const float* cbp = cb + (size_t)phi_idx[si]*C_;
        k_upphi<<<B_*8, 256, 0, stream>>>(best, emb, cwp, cbp, f, f_hat, f_rest,
                                          lossAcc, pn);
    }
    k_final<<<1024, 256, 0, stream>>>(f_hat, lossAcc, out);
}

// Round 5
// 498.137 us; speedup vs baseline: 5.5889x; 1.1056x over previous
//
#include <hip/hip_runtime.h>
#include <math.h>
#include <stdint.h>

#define B_ 32
#define C_ 32
#define H_ 16
#define V_ 8192
#define HW_ 256
#define NELEM (B_*C_*H_*H_)   // 262144
#define TBYTES 6208           // per 16-code tile: 3*2048 frag planes + 64 e2sq
#define TF4    388            // TBYTES/16

typedef short bf16x8 __attribute__((ext_vector_type(8)));
typedef unsigned short u16x8 __attribute__((ext_vector_type(8)));
typedef float f32x4 __attribute__((ext_vector_type(4)));
typedef unsigned long long ull;

__device__ __forceinline__ unsigned int fkey(float f) {
    unsigned int u = __float_as_uint(f);
    return (u & 0x80000000u) ? ~u : (u | 0x80000000u);
}
__device__ __forceinline__ unsigned short f2bf(float x) {
    unsigned int u = __float_as_uint(x);
    unsigned int r = u + 0x7fffu + ((u >> 16) & 1u);
    return (unsigned short)(r >> 16);
}
__device__ __forceinline__ float bf2f(unsigned short h) {
    return __uint_as_float(((unsigned int)h) << 16);
}

// init f_rest/f_hat; build E-fragment blob: per tile t (16 codes):
//  [0..2048) bf16 plane0 of -2E in A-frag order, [2048..4096) plane1,
//  [4096..6144) plane2, [6144..6208) e2sq[16] f32
__global__ void __launch_bounds__(256) k_init(
    const float* __restrict__ f, const float* __restrict__ emb,
    float* __restrict__ f_rest, float* __restrict__ f_hat,
    char* __restrict__ blob, float* __restrict__ lossAcc)
{
    int i = blockIdx.x*256 + threadIdx.x;
    if (i < NELEM) { float v = f[i]; f_rest[i] = v; f_hat[i] = 0.f; }
    if (i < 512*64) {
        int t = i >> 6, l = i & 63;
        int row = t*16 + (l & 15);
        int k0 = (l >> 4) * 8;
        const float* er = emb + row*C_ + k0;
        u16x8 h0, h1, h2;
        #pragma unroll
        for (int j = 0; j < 8; ++j) {
            float x = -2.f * er[j];
            unsigned short b0 = f2bf(x);  float r1 = x - bf2f(b0);
            unsigned short b1 = f2bf(r1); float r2 = r1 - bf2f(b1);
            unsigned short b2 = f2bf(r2);
            h0[j] = b0; h1[j] = b1; h2[j] = b2;
        }
        char* tb = blob + (size_t)t*TBYTES;
        *(u16x8*)(tb +        l*16) = h0;
        *(u16x8*)(tb + 2048 + l*16) = h1;
        *(u16x8*)(tb + 4096 + l*16) = h2;
        if ((l >> 4) == 0) {
            const float4* e4 = (const float4*)(emb + row*C_);
            float s = 0.f;
            #pragma unroll
            for (int cc = 0; cc < 8; ++cc) {
                float4 ev = e4[cc];
                s += ev.x*ev.x + ev.y*ev.y + ev.z*ev.z + ev.w*ev.w;
            }
            *(float*)(tb + 6144 + (l & 15)*4) = s;
        }
    }
    if (i == 0) lossAcc[0] = 0.f;
}

// area pool f_rest -> zb bf16x3 split planes [3][8192][32]; init best slots
__global__ void __launch_bounds__(256) k_pool(
    const float* __restrict__ f_rest, unsigned short* __restrict__ zb,
    ull* __restrict__ best, int pn, int N)
{
    int gid = blockIdx.x*256 + threadIdx.x;
    if (gid >= N*C_) return;
    int c = gid & 31;
    int n = gid >> 5;
    if (c == 0) best[n] = ~0ull;
    int pp = pn*pn;
    int b = n / pp;
    int rem = n - b*pp;
    int p = rem / pn;
    int q = rem - p*pn;
    int hs = (p*H_)/pn,  he = ((p+1)*H_ + pn-1)/pn;
    int ws = (q*H_)/pn,  we = ((q+1)*H_ + pn-1)/pn;
    const float* base = f_rest + ((size_t)(b*C_ + c))*HW_;
    float s = 0.f;
    for (int hh = hs; hh < he; ++hh) {
        #pragma unroll 4
        for (int ww = ws; ww < we; ++ww)
            s += base[hh*H_ + ww];
    }
    float inv = (1.f/(float)(he-hs)) * (1.f/(float)(we-ws));
    float x = s * inv;
    unsigned short b0 = f2bf(x);  float r1 = x - bf2f(b0);
    unsigned short b1 = f2bf(r1); float r2 = r1 - bf2f(b1);
    unsigned short b2 = f2bf(r2);
    size_t o = (size_t)n*C_ + c;
    zb[o]          = b0;
    zb[o + 262144] = b1;
    zb[o + 524288] = b2;
}

// MFMA VQ: block = 128 queries (4 waves x 2 query-tiles) x V-chunk.
// E-tiles staged to LDS in fragment order; D[code][query] per 16x16 MFMA;
// per-lane running argmin; shfl_xor + atomicMin(best) combine.
__global__ void __launch_bounds__(256) k_vqm(
    const float4* __restrict__ blob, const unsigned short* __restrict__ zb,
    ull* __restrict__ best, int N, int lvs)
{
    __shared__ char chunk[8*TBYTES] __attribute__((aligned(16)));
    int tid = threadIdx.x, lane = tid & 63, w = tid >> 6;
    int qb = blockIdx.x >> lvs;
    int vc = blockIdx.x & ((1 << lvs) - 1);
    int tiles_total = 512 >> lvs;
    int t0 = vc * tiles_total;
    int qt0 = qb*8 + w*2;
    int qr = lane & 15, kq = lane >> 4;

    // B-fragments: lane holds Z[q=qt*16+qr][k0..k0+7] per split plane
    bf16x8 B00, B01, B02, B10, B11, B12;
    {
        size_t r0 = (size_t)(qt0*16 + qr)*C_ + kq*8;
        size_t r1 = r0 + 16*C_;
        B00 = *(const bf16x8*)(zb + r0);
        B01 = *(const bf16x8*)(zb + r0 + 262144);
        B02 = *(const bf16x8*)(zb + r0 + 524288);
        B10 = *(const bf16x8*)(zb + r1);
        B11 = *(const bf16x8*)(zb + r1 + 262144);
        B12 = *(const bf16x8*)(zb + r1 + 524288);
    }

    float dmin0 = __builtin_inff(), dmin1 = __builtin_inff();
    int imin0 = 0, imin1 = 0;

    for (int tc = 0; tc < tiles_total; tc += 8) {
        int S = (tiles_total - tc) < 8 ? (tiles_total - tc) : 8;
        int cnt = S * TF4;
        __syncthreads();
        const float4* src = blob + (size_t)(t0 + tc)*TF4;
        for (int i = tid; i < cnt; i += 256)
            ((float4*)chunk)[i] = src[i];
        __syncthreads();
        for (int t = 0; t < S; ++t) {
            const char* tb = chunk + t*TBYTES;
            bf16x8 A0 = *(const bf16x8*)(tb +        lane*16);
            bf16x8 A1 = *(const bf16x8*)(tb + 2048 + lane*16);
            bf16x8 A2 = *(const bf16x8*)(tb + 4096 + lane*16);
            f32x4 e2v = *(const f32x4*)(tb + 6144 + kq*16);
            f32x4 a0 = e2v, a1 = e2v;
            #define MF(Af, Bf, Cc) Cc = __builtin_amdgcn_mfma_f32_16x16x32_bf16(Af, Bf, Cc, 0, 0, 0)
            MF(A0, B00, a0); MF(A0, B10, a1);   // e0 z0
            MF(A1, B00, a0); MF(A1, B10, a1);   // e1 z0
            MF(A0, B01, a0); MF(A0, B11, a1);   // e0 z1
            MF(A2, B00, a0); MF(A2, B10, a1);   // e2 z0
            MF(A1, B01, a0); MF(A1, B11, a1);   // e1 z1
            MF(A0, B02, a0); MF(A0, B12, a1);   // e0 z2
            MF(A2, B01, a0); MF(A2, B11, a1);   // e2 z1
            MF(A1, B02, a0); MF(A1, B12, a1);   // e1 z2
            #undef MF
            int cbase = (t0 + tc + t)*16 + kq*4;
            float mt0 = fminf(fminf(a0.x, a0.y), fminf(a0.z, a0.w));
            if (mt0 < dmin0) {
                dmin0 = mt0;
                imin0 = cbase + ((a0.x==mt0) ? 0 : (a0.y==mt0) ? 1 : (a0.z==mt0) ? 2 : 3);
            }
            float mt1 = fminf(fminf(a1.x, a1.y), fminf(a1.z, a1.w));
            if (mt1 < dmin1) {
                dmin1 = mt1;
                imin1 = cbase + ((a1.x==mt1) ? 0 : (a1.y==mt1) ? 1 : (a1.z==mt1) ? 2 : 3);
            }
        }
    }

    ull k0 = ((ull)fkey(dmin0) << 32) | (unsigned int)imin0;
    ull k1 = ((ull)fkey(dmin1) << 32) | (unsigned int)imin1;
    #pragma unroll
    for (int off = 16; off <= 32; off <<= 1) {
        ull o0 = __shfl_xor(k0, off);
        ull o1 = __shfl_xor(k1, off);
        k0 = o0 < k0 ? o0 : k0;
        k1 = o1 < k1 ? o1 : k1;
    }
    if (kq == 0) {
        int q0 = qt0*16 + qr;
        int q1 = q0 + 16;
        if (q0 < N) atomicMin(best + q0, k0);
        if (q1 < N) atomicMin(best + q1, k1);
    }
}

__device__ __forceinline__ void cubic_taps(int i, int pn, float* wt, int* col) {
    double src = ((double)i + 0.5) * ((double)pn / 16.0) - 0.5;
    double fl = floor(src);
    const double A = -0.75;
    #pragma unroll
    for (int k = 0; k < 4; ++k) {
        double j = fl - 1.0 + (double)k;
        double d = fabs(src - j);
        double w;
        if (d <= 1.0)      w = ((A+2.0)*d - (A+3.0))*d*d + 1.0;
        else if (d < 2.0)  w = ((A*d - 5.0*A)*d + 8.0*A)*d - 4.0*A;
        else               w = 0.0;
        wt[k] = (float)w;
        int jj = (int)j;
        col[k] = jj < 0 ? 0 : (jj > pn-1 ? pn-1 : jj);
    }
}

// bicubic upsample (emb gather) -> LDS, 3x3 conv + Phi blend,
// f_hat += , f_rest -= , loss partial
__global__ void __launch_bounds__(256) k_upphi(
    const ull* __restrict__ best,
    const float* __restrict__ emb,
    const float* __restrict__ cw, const float* __restrict__ cb,
    const float* __restrict__ forig,
    float* __restrict__ f_hat, float* __restrict__ f_rest,
    float* __restrict__ lossAcc, int pn)
{
    __shared__ float hup[16][16][33];
    __shared__ float red[4];
    int bi = blockIdx.x >> 3;
    int g  = blockIdx.x & 7;
    int tid = threadIdx.x;
    int h = tid >> 4, w = tid & 15;

    float wh[4]; int th[4];
    float wwt[4]; int tw[4];
    cubic_taps(h, pn, wh, th);
    cubic_taps(w, pn, wwt, tw);

    float acc[32];
    #pragma unroll
    for (int c = 0; c < 32; ++c) acc[c] = 0.f;
    const ull* bptr = best + bi*pn*pn;
    for (int i = 0; i < 4; ++i) {
        if (wh[i] == 0.f) continue;
        for (int j = 0; j < 4; ++j) {
            float wt = wh[i]*wwt[j];
            if (wt == 0.f) continue;
            unsigned int idx = (unsigned int)(bptr[th[i]*pn + tw[j]] & 0xffffffffull);
            const float4* e4 = (const float4*)(emb + (size_t)idx*C_);
            #pragma unroll
            for (int cc = 0; cc < 8; ++cc) {
                float4 ev = e4[cc];
                acc[cc*4+0] = fmaf(wt, ev.x, acc[cc*4+0]);
                acc[cc*4+1] = fmaf(wt, ev.y, acc[cc*4+1]);
                acc[cc*4+2] = fmaf(wt, ev.z, acc[cc*4+2]);
                acc[cc*4+3] = fmaf(wt, ev.w, acc[cc*4+3]);
            }
        }
    }
    #pragma unroll
    for (int c = 0; c < 32; ++c) hup[h][w][c] = acc[c];
    __syncthreads();

    int co0 = g*4;
    float o4[4];
    #pragma unroll
    for (int k = 0; k < 4; ++k) o4[k] = cb[co0+k];
    for (int ci = 0; ci < 32; ++ci) {
        float hv[9];
        #pragma unroll
        for (int dh = 0; dh < 3; ++dh) {
            int hh = h + dh - 1;
            #pragma unroll
            for (int dw = 0; dw < 3; ++dw) {
                int ww2 = w + dw - 1;
                bool ok = (hh >= 0) & (hh < 16) & (ww2 >= 0) & (ww2 < 16);
                hv[dh*3+dw] = ok ? hup[hh & 15][ww2 & 15][ci] : 0.f;
            }
        }
        #pragma unroll
        for (int k = 0; k < 4; ++k) {
            const float* wr = cw + ((size_t)(co0+k)*C_ + ci)*9;
            float s = 0.f;
            #pragma unroll
            for (int p2 = 0; p2 < 9; ++p2) s = fmaf(hv[p2], wr[p2], s);
            o4[k] += s;
        }
    }

    float sq = 0.f;
    #pragma unroll
    for (int k = 0; k < 4; ++k) {
        float hv0 = hup[h][w][co0+k];
        float outv = 0.5f*hv0 + 0.5f*o4[k];
        size_t off = ((size_t)(bi*C_ + co0 + k))*HW_ + h*16 + w;
        float fh = f_hat[off] + outv;
        f_hat[off] = fh;
        f_rest[off] = f_rest[off] - outv;
        float df = fh - forig[off];
        sq = fmaf(df, df, sq);
    }
    #pragma unroll
    for (int o2 = 32; o2 > 0; o2 >>= 1) sq += __shfl_down(sq, o2, 64);
    if ((tid & 63) == 0) red[tid >> 6] = sq;
    __syncthreads();
    if (tid == 0) atomicAdd(lossAcc, (red[0]+red[1])+(red[2]+red[3]));
}

__global__ void __launch_bounds__(256) k_final(
    const float* __restrict__ f_hat, const float* __restrict__ lossAcc,
    float* __restrict__ out)
{
    int i = blockIdx.x*256 + threadIdx.x;
    if (i < NELEM) out[i] = f_hat[i];
    if (i == 0) out[NELEM] = lossAcc[0] * 1.25f / ((float)NELEM * 10.f);
}

extern "C" void kernel_launch(void* const* d_in, const int* in_sizes, int n_in,
                              void* d_out, int out_size, void* d_ws, size_t ws_size,
                              hipStream_t stream)
{
    const float* f   = (const float*)d_in[0];
    const float* emb = (const float*)d_in[1];
    const float* cw  = (const float*)d_in[2];
    const float* cb  = (const float*)d_in[3];
    float* out = (float*)d_out;
    char* ws = (char*)d_ws;
    ull*   best   = (ull*)ws;                                  // 64 KB
    float* f_rest = (float*)(ws + 65536);                      // 1 MB
    float* f_hat  = (float*)(ws + 65536 + 1048576);            // 1 MB
    unsigned short* zb = (unsigned short*)(ws + 2162688);      // 1.5 MB
    char*  blob   = ws + 3735552;                              // 512*6208 B
    float* lossAcc = (float*)(ws + 3735552 + 512*TBYTES);

    // Replicate PHI_IDX with numpy-linspace double semantics (no FP contraction)
    volatile double a   = 1.0/3.0/4.0;
    volatile double bb  = 1.0 - a;
    volatile double stp = (bb - a) / 3.0;
    double ticks[4];
    for (int i = 0; i < 4; ++i) { volatile double m = (double)i * stp; ticks[i] = m + a; }
    ticks[3] = bb;
    static const int pns[10] = {1,2,3,4,5,6,8,10,13,16};
    int phi_idx[10];
    for (int si = 0; si < 10; ++si) {
        volatile double x = (double)si / 9.0;
        int bi = 0; double bd = fabs(ticks[0] - x);
        for (int k = 1; k < 4; ++k) {
            double d = fabs(ticks[k] - x);
            if (d < bd) { bd = d; bi = k; }
        }
        phi_idx[si] = bi;
    }

    k_init<<<1024, 256, 0, stream>>>(f, emb, f_rest, f_hat, blob, lossAcc);

    // per-scale log2(V-split): grid = ceil(N/128) << lvs, code-tiles/block = 512>>lvs
    static const int lvss[10] = {7,7,7,7,6,6,5,4,4,3};
    for (int si = 0; si < 10; ++si) {
        int pn = pns[si];
        int N = B_*pn*pn;
        int pthr = N*C_;
        k_pool<<<(pthr+255)/256, 256, 0, stream>>>(f_rest, zb, best, pn, N);
        int qtiles = (N + 127)/128;
        int lvs = lvss[si];
        k_vqm<<<qtiles << lvs, 256, 0, stream>>>((const float4*)blob, zb, best, N, lvs);
        const float* cwp = cw + (size_t)phi_idx[si]*C_*C_*9;
        const float* cbp = cb + (size_t)phi_idx[si]*C_;
        k_upphi<<<B_*8, 256, 0, stream>>>(best, emb, cwp, cbp, f, f_hat, f_rest,
                                          lossAcc, pn);
    }
    k_final<<<1024, 256, 0, stream>>>(f_hat, lossAcc, out);
}

// Round 7
// 437.056 us; speedup vs baseline: 6.3700x; 1.1398x over previous
//
#include <hip/hip_runtime.h>
#include <math.h>
#include <stdint.h>

#define B_ 32
#define C_ 32
#define H_ 16
#define V_ 8192
#define HW_ 256
#define NELEM (B_*C_*H_*H_)   // 262144
#define TBYTES 6208           // per 16-code tile: 3*2048 frag planes + 64 e2sq
#define ZPL 262144            // zb plane stride (elements)

typedef short bf16x8 __attribute__((ext_vector_type(8)));
typedef unsigned short u16x8 __attribute__((ext_vector_type(8)));
typedef float f32x4 __attribute__((ext_vector_type(4)));
typedef unsigned long long ull;

__device__ __forceinline__ unsigned int fkey(float f) {
    unsigned int u = __float_as_uint(f);
    return (u & 0x80000000u) ? ~u : (u | 0x80000000u);
}
__device__ __forceinline__ unsigned short f2bf(float x) {
    unsigned int u = __float_as_uint(x);
    unsigned int r = u + 0x7fffu + ((u >> 16) & 1u);
    return (unsigned short)(r >> 16);
}
__device__ __forceinline__ float bf2f(unsigned short h) {
    return __uint_as_float(((unsigned int)h) << 16);
}

// init f_rest/f_hat; build E-fragment blob (A-frag order, -2E bf16x3 + e2sq)
__global__ void __launch_bounds__(256) k_init(
    const float* __restrict__ f, const float* __restrict__ emb,
    float* __restrict__ f_rest, float* __restrict__ f_hat,
    char* __restrict__ blob, float* __restrict__ lossAcc)
{
    int i = blockIdx.x*256 + threadIdx.x;
    if (i < NELEM) { float v = f[i]; f_rest[i] = v; f_hat[i] = 0.f; }
    if (i < 512*64) {
        int t = i >> 6, l = i & 63;
        int row = t*16 + (l & 15);
        int k0 = (l >> 4) * 8;
        const float* er = emb + row*C_ + k0;
        u16x8 h0, h1, h2;
        #pragma unroll
        for (int j = 0; j < 8; ++j) {
            float x = -2.f * er[j];
            unsigned short b0 = f2bf(x);  float r1 = x - bf2f(b0);
            unsigned short b1 = f2bf(r1); float r2 = r1 - bf2f(b1);
            unsigned short b2 = f2bf(r2);
            h0[j] = b0; h1[j] = b1; h2[j] = b2;
        }
        char* tb = blob + (size_t)t*TBYTES;
        *(u16x8*)(tb +        l*16) = h0;
        *(u16x8*)(tb + 2048 + l*16) = h1;
        *(u16x8*)(tb + 4096 + l*16) = h2;
        if ((l >> 4) == 0) {
            const float4* e4 = (const float4*)(emb + row*C_);
            float s = 0.f;
            #pragma unroll
            for (int cc = 0; cc < 8; ++cc) {
                float4 ev = e4[cc];
                s += ev.x*ev.x + ev.y*ev.y + ev.z*ev.z + ev.w*ev.w;
            }
            *(float*)(tb + 6144 + (l & 15)*4) = s;
        }
    }
    if (i == 0) lossAcc[0] = 0.f;
}

// area pool (used only for scale 0, pn=1) -> zb bf16x3 planes; init best
__global__ void __launch_bounds__(256) k_pool(
    const float* __restrict__ f_rest, unsigned short* __restrict__ zb,
    ull* __restrict__ best, int pn, int N)
{
    int gid = blockIdx.x*256 + threadIdx.x;
    if (gid >= N*C_) return;
    int c = gid & 31;
    int n = gid >> 5;
    if (c == 0) best[n] = ~0ull;
    int pp = pn*pn;
    int b = n / pp;
    int rem = n - b*pp;
    int p = rem / pn;
    int q = rem - p*pn;
    int hs = (p*H_)/pn,  he = ((p+1)*H_ + pn-1)/pn;
    int ws = (q*H_)/pn,  we = ((q+1)*H_ + pn-1)/pn;
    const float* base = f_rest + ((size_t)(b*C_ + c))*HW_;
    float s = 0.f;
    for (int hh = hs; hh < he; ++hh)
        for (int ww = ws; ww < we; ++ww)
            s += base[hh*H_ + ww];
    float inv = (1.f/(float)(he-hs)) * (1.f/(float)(we-ws));
    float x = s * inv;
    unsigned short b0 = f2bf(x);  float r1 = x - bf2f(b0);
    unsigned short b1 = f2bf(r1); float r2 = r1 - bf2f(b1);
    unsigned short b2 = f2bf(r2);
    size_t o = (size_t)n*C_ + c;
    zb[o] = b0; zb[o + ZPL] = b1; zb[o + 2*ZPL] = b2;
}

// one query-tile distance step: 6 MFMA (bf16x3 split, s+t<=2) + running argmin
__device__ __forceinline__ void qstep(
    const bf16x8 a0, const bf16x8 a1, const bf16x8 a2, const f32x4 e2v,
    const bf16x8* Bf, int cbase, float& dmin, int& imin)
{
    f32x4 acc = e2v;
    acc = __builtin_amdgcn_mfma_f32_16x16x32_bf16(a0, Bf[0], acc, 0, 0, 0);
    acc = __builtin_amdgcn_mfma_f32_16x16x32_bf16(a1, Bf[0], acc, 0, 0, 0);
    acc = __builtin_amdgcn_mfma_f32_16x16x32_bf16(a0, Bf[1], acc, 0, 0, 0);
    acc = __builtin_amdgcn_mfma_f32_16x16x32_bf16(a2, Bf[0], acc, 0, 0, 0);
    acc = __builtin_amdgcn_mfma_f32_16x16x32_bf16(a1, Bf[1], acc, 0, 0, 0);
    acc = __builtin_amdgcn_mfma_f32_16x16x32_bf16(a0, Bf[2], acc, 0, 0, 0);
    float mt = fminf(fminf(acc.x, acc.y), fminf(acc.z, acc.w));
    if (mt < dmin) {
        dmin = mt;
        imin = cbase + ((acc.x==mt) ? 0 : (acc.y==mt) ? 1 : (acc.z==mt) ? 2 : 3);
    }
}

// MFMA VQ: wave = 4 query-tiles x V-chunk; A-frags read direct from global
// (L2-resident blob), register double-buffered; no LDS, no barriers.
__global__ void __launch_bounds__(256, 2) k_vqm(
    const char* __restrict__ blob, const unsigned short* __restrict__ zb,
    ull* __restrict__ best, int N, int lvs)
{
    int tid = threadIdx.x, lane = tid & 63, w = tid >> 6;
    int qtiles_total = N >> 4;
    int qb = blockIdx.x >> lvs;
    int vc = blockIdx.x & ((1 << lvs) - 1);
    int tiles = 512 >> lvs;
    int t0 = vc * tiles;
    int qt0 = qb*16 + w*4;
    int qr = lane & 15, kq = lane >> 4;

    bf16x8 Bf0[3], Bf1[3], Bf2[3], Bf3[3];
    int qv0, qv1, qv2, qv3;
    {
        int qtj;
        size_t o;
        qtj = qt0 + 0; qv0 = (qtj < qtiles_total);
        o = (size_t)((qv0 ? qtj : 0)*16 + qr)*C_ + kq*8;
        Bf0[0] = *(const bf16x8*)(zb + o);
        Bf0[1] = *(const bf16x8*)(zb + o + ZPL);
        Bf0[2] = *(const bf16x8*)(zb + o + 2*ZPL);
        qtj = qt0 + 1; qv1 = (qtj < qtiles_total);
        o = (size_t)((qv1 ? qtj : 0)*16 + qr)*C_ + kq*8;
        Bf1[0] = *(const bf16x8*)(zb + o);
        Bf1[1] = *(const bf16x8*)(zb + o + ZPL);
        Bf1[2] = *(const bf16x8*)(zb + o + 2*ZPL);
        qtj = qt0 + 2; qv2 = (qtj < qtiles_total);
        o = (size_t)((qv2 ? qtj : 0)*16 + qr)*C_ + kq*8;
        Bf2[0] = *(const bf16x8*)(zb + o);
        Bf2[1] = *(const bf16x8*)(zb + o + ZPL);
        Bf2[2] = *(const bf16x8*)(zb + o + 2*ZPL);
        qtj = qt0 + 3; qv3 = (qtj < qtiles_total);
        o = (size_t)((qv3 ? qtj : 0)*16 + qr)*C_ + kq*8;
        Bf3[0] = *(const bf16x8*)(zb + o);
        Bf3[1] = *(const bf16x8*)(zb + o + ZPL);
        Bf3[2] = *(const bf16x8*)(zb + o + 2*ZPL);
    }

    float dmin[4]; int imin[4];
    #pragma unroll
    for (int j = 0; j < 4; ++j) { dmin[j] = __builtin_inff(); imin[j] = 0; }

    const char* tb = blob + (size_t)t0*TBYTES;
    bf16x8 Xa0, Xa1, Xa2; f32x4 Xe;
    bf16x8 Ya0, Ya1, Ya2; f32x4 Ye;
    Xa0 = *(const bf16x8*)(tb +        lane*16);
    Xa1 = *(const bf16x8*)(tb + 2048 + lane*16);
    Xa2 = *(const bf16x8*)(tb + 4096 + lane*16);
    Xe  = *(const f32x4*)(tb + 6144 + kq*16);

    for (int tt = 0; tt < tiles; tt += 2) {
        const char* nb = tb + TBYTES;
        Ya0 = *(const bf16x8*)(nb +        lane*16);
        Ya1 = *(const bf16x8*)(nb + 2048 + lane*16);
        Ya2 = *(const bf16x8*)(nb + 4096 + lane*16);
        Ye  = *(const f32x4*)(nb + 6144 + kq*16);
        {
            int cbase = (t0 + tt)*16 + kq*4;
            qstep(Xa0, Xa1, Xa2, Xe, Bf0, cbase, dmin[0], imin[0]);
            qstep(Xa0, Xa1, Xa2, Xe, Bf1, cbase, dmin[1], imin[1]);
            qstep(Xa0, Xa1, Xa2, Xe, Bf2, cbase, dmin[2], imin[2]);
            qstep(Xa0, Xa1, Xa2, Xe, Bf3, cbase, dmin[3], imin[3]);
        }
        const char* nb2 = (tt + 2 < tiles) ? tb + 2*TBYTES : tb;
        Xa0 = *(const bf16x8*)(nb2 +        lane*16);
        Xa1 = *(const bf16x8*)(nb2 + 2048 + lane*16);
        Xa2 = *(const bf16x8*)(nb2 + 4096 + lane*16);
        Xe  = *(const f32x4*)(nb2 + 6144 + kq*16);
        {
            int cbase = (t0 + tt + 1)*16 + kq*4;
            qstep(Ya0, Ya1, Ya2, Ye, Bf0, cbase, dmin[0], imin[0]);
            qstep(Ya0, Ya1, Ya2, Ye, Bf1, cbase, dmin[1], imin[1]);
            qstep(Ya0, Ya1, Ya2, Ye, Bf2, cbase, dmin[2], imin[2]);
            qstep(Ya0, Ya1, Ya2, Ye, Bf3, cbase, dmin[3], imin[3]);
        }
        tb += 2*TBYTES;
    }

    int qvv[4] = {qv0, qv1, qv2, qv3};
    #pragma unroll
    for (int j = 0; j < 4; ++j) {
        ull key = ((ull)fkey(dmin[j]) << 32) | (unsigned int)imin[j];
        ull o1 = __shfl_xor(key, 16); key = o1 < key ? o1 : key;
        ull o2 = __shfl_xor(key, 32); key = o2 < key ? o2 : key;
        if (kq == 0 && qvv[j]) {
            int q = (qt0 + j)*16 + qr;
            atomicMin(best + q, key);
        }
    }
}

__device__ __forceinline__ void cubic_taps(int i, int pn, float* wt, int* col) {
    double src = ((double)i + 0.5) * ((double)pn / 16.0) - 0.5;
    double fl = floor(src);
    const double A = -0.75;
    #pragma unroll
    for (int k = 0; k < 4; ++k) {
        double j = fl - 1.0 + (double)k;
        double d = fabs(src - j);
        double w;
        if (d <= 1.0)      w = ((A+2.0)*d - (A+3.0))*d*d + 1.0;
        else if (d < 2.0)  w = ((A*d - 5.0*A)*d + 8.0*A)*d - 4.0*A;
        else               w = 0.0;
        wt[k] = (float)w;
        int jj = (int)j;
        col[k] = jj < 0 ? 0 : (jj > pn-1 ? pn-1 : jj);
    }
}

// bicubic upsample -> LDS, 3x3 conv + Phi blend, f_hat/f_rest update, loss;
// FUSED: area-pool new f_rest for NEXT scale -> zb planes + init next best
__global__ void __launch_bounds__(256) k_upphi(
    const ull* __restrict__ best,
    const float* __restrict__ emb,
    const float* __restrict__ cw, const float* __restrict__ cb,
    const float* __restrict__ forig,
    float* __restrict__ f_hat, float* __restrict__ f_rest,
    float* __restrict__ lossAcc, int pn,
    int pn2, unsigned short* __restrict__ zb, ull* __restrict__ bestN)
{
    __shared__ float hup[16][16][33];
    __shared__ float red[4];
    int bi = blockIdx.x >> 3;
    int g  = blockIdx.x & 7;
    int tid = threadIdx.x;
    int h = tid >> 4, w = tid & 15;

    float wh[4]; int th[4];
    float wwt[4]; int tw[4];
    cubic_taps(h, pn, wh, th);
    cubic_taps(w, pn, wwt, tw);

    float acc[32];
    #pragma unroll
    for (int c = 0; c < 32; ++c) acc[c] = 0.f;
    const ull* bptr = best + bi*pn*pn;
    for (int i = 0; i < 4; ++i) {
        if (wh[i] == 0.f) continue;
        for (int j = 0; j < 4; ++j) {
            float wt = wh[i]*wwt[j];
            if (wt == 0.f) continue;
            unsigned int idx = (unsigned int)(bptr[th[i]*pn + tw[j]] & 0xffffffffull);
            const float4* e4 = (const float4*)(emb + (size_t)idx*C_);
            #pragma unroll
            for (int cc = 0; cc < 8; ++cc) {
                float4 ev = e4[cc];
                acc[cc*4+0] = fmaf(wt, ev.x, acc[cc*4+0]);
                acc[cc*4+1] = fmaf(wt, ev.y, acc[cc*4+1]);
                acc[cc*4+2] = fmaf(wt, ev.z, acc[cc*4+2]);
                acc[cc*4+3] = fmaf(wt, ev.w, acc[cc*4+3]);
            }
        }
    }
    #pragma unroll
    for (int c = 0; c < 32; ++c) hup[h][w][c] = acc[c];
    __syncthreads();

    int co0 = g*4;
    float o4[4];
    #pragma unroll
    for (int k = 0; k < 4; ++k) o4[k] = cb[co0+k];
    for (int ci = 0; ci < 32; ++ci) {
        float hv[9];
        #pragma unroll
        for (int dh = 0; dh < 3; ++dh) {
            int hh = h + dh - 1;
            #pragma unroll
            for (int dw = 0; dw < 3; ++dw) {
                int ww2 = w + dw - 1;
                bool ok = (hh >= 0) & (hh < 16) & (ww2 >= 0) & (ww2 < 16);
                hv[dh*3+dw] = ok ? hup[hh & 15][ww2 & 15][ci] : 0.f;
            }
        }
        #pragma unroll
        for (int k = 0; k < 4; ++k) {
            const float* wr = cw + ((size_t)(co0+k)*C_ + ci)*9;
            float s = 0.f;
            #pragma unroll
            for (int p2 = 0; p2 < 9; ++p2) s = fmaf(hv[p2], wr[p2], s);
            o4[k] += s;
        }
    }
    __syncthreads();   // all conv reads of hup complete

    float sq = 0.f;
    #pragma unroll
    for (int k = 0; k < 4; ++k) {
        float hv0 = hup[h][w][co0+k];
        float outv = 0.5f*hv0 + 0.5f*o4[k];
        size_t off = ((size_t)(bi*C_ + co0 + k))*HW_ + h*16 + w;
        float fh = f_hat[off] + outv;
        f_hat[off] = fh;
        float fr = f_rest[off] - outv;
        f_rest[off] = fr;
        hup[h][w][co0+k] = fr;          // stash new f_rest for fused pool
        float df = fh - forig[off];
        sq = fmaf(df, df, sq);
    }
    #pragma unroll
    for (int o2 = 32; o2 > 0; o2 >>= 1) sq += __shfl_down(sq, o2, 64);
    if ((tid & 63) == 0) red[tid >> 6] = sq;
    __syncthreads();
    if (tid == 0) atomicAdd(lossAcc, (red[0]+red[1])+(red[2]+red[3]));

    // fused area-pool for next scale
    if (pn2 > 0 && h < pn2 && w < pn2) {
        int hs = (h*H_)/pn2,  he2 = ((h+1)*H_ + pn2-1)/pn2;
        int ws2 = (w*H_)/pn2, we2 = ((w+1)*H_ + pn2-1)/pn2;
        float inv = (1.f/(float)(he2-hs)) * (1.f/(float)(we2-ws2));
        int n = bi*pn2*pn2 + h*pn2 + w;
        #pragma unroll
        for (int k = 0; k < 4; ++k) {
            float s = 0.f;
            for (int hh = hs; hh < he2; ++hh)
                for (int ww = ws2; ww < we2; ++ww)
                    s += hup[hh][ww][co0+k];
            float x = s * inv;
            unsigned short b0 = f2bf(x);  float r1 = x - bf2f(b0);
            unsigned short b1 = f2bf(r1); float r2 = r1 - bf2f(b1);
            unsigned short b2 = f2bf(r2);
            size_t o = (size_t)n*C_ + co0 + k;
            zb[o] = b0; zb[o + ZPL] = b1; zb[o + 2*ZPL] = b2;
        }
        if (g == 0) bestN[n] = ~0ull;
    }
}

__global__ void __launch_bounds__(256) k_final(
    const float* __restrict__ f_hat, const float* __restrict__ lossAcc,
    float* __restrict__ out)
{
    int i = blockIdx.x*256 + threadIdx.x;
    if (i < NELEM) out[i] = f_hat[i];
    if (i == 0) out[NELEM] = lossAcc[0] * 1.25f / ((float)NELEM * 10.f);
}

extern "C" void kernel_launch(void* const* d_in, const int* in_sizes, int n_in,
                              void* d_out, int out_size, void* d_ws, size_t ws_size,
                              hipStream_t stream)
{
    const float* f   = (const float*)d_in[0];
    const float* emb = (const float*)d_in[1];
    const float* cw  = (const float*)d_in[2];
    const float* cb  = (const float*)d_in[3];
    float* out = (float*)d_out;
    char* ws = (char*)d_ws;
    ull*   best0  = (ull*)ws;                                  // 64 KB
    ull*   best1  = (ull*)(ws + 65536);                        // 64 KB
    float* f_rest = (float*)(ws + 131072);                     // 1 MB
    float* f_hat  = (float*)(ws + 131072 + 1048576);           // 1 MB
    unsigned short* zb = (unsigned short*)(ws + 2228224);      // 1.5 MB
    char*  blob   = ws + 3801088;                              // 512*6208 B
    float* lossAcc = (float*)(ws + 6979584);

    // Replicate PHI_IDX with numpy-linspace double semantics (no FP contraction)
    volatile double a   = 1.0/3.0/4.0;
    volatile double bb  = 1.0 - a;
    volatile double stp = (bb - a) / 3.0;
    double ticks[4];
    for (int i = 0; i < 4; ++i) { volatile double m = (double)i * stp; ticks[i] = m + a; }
    ticks[3] = bb;
    static const int pns[10] = {1,2,3,4,5,6,8,10,13,16};
    int phi_idx[10];
    for (int si = 0; si < 10; ++si) {
        volatile double x = (double)si / 9.0;
        int bi = 0; double bd = fabs(ticks[0] - x);
        for (int k = 1; k < 4; ++k) {
            double d = fabs(ticks[k] - x);
            if (d < bd) { bd = d; bi = k; }
        }
        phi_idx[si] = bi;
    }

    k_init<<<1024, 256, 0, stream>>>(f, emb, f_rest, f_hat, blob, lossAcc);
    k_pool<<<4, 256, 0, stream>>>(f_rest, zb, best0, 1, 32);

    static const int lvss[10] = {6,6,6,6,6,6,6,5,5,4};
    for (int si = 0; si < 10; ++si) {
        int pn = pns[si];
        int N = B_*pn*pn;
        int qtiles = N >> 4;
        int qblocks = (qtiles + 15)/16;
        int lvs = lvss[si];
        ull* bcur  = (si & 1) ? best1 : best0;
        ull* bnext = (si & 1) ? best0 : best1;
        k_vqm<<<qblocks << lvs, 256, 0, stream>>>(blob, zb, bcur, N, lvs);
        const float* cwp = cw + (size_t)phi_idx[si]*C_*C_*9;
        const float* cbp = cb + (size_t)phi_idx[si]*C_;
        int pn2 = (si < 9) ? pns[si+1] : 0;
        k_upphi<<<B_*8, 256, 0, stream>>>(bcur, emb, cwp, cbp, f, f_hat, f_rest,
                                          lossAcc, pn, pn2, zb, bnext);
    }
    k_final<<<1024, 256, 0, stream>>>(f_hat, lossAcc, out);
}